// Round 10
// baseline (151.671 us; speedup 1.0000x reference)
//
#include <hip/hip_runtime.h>
#include <hip/hip_bf16.h>
#include <stdint.h>

#define WW    361    // W*W spatial positions
#define CCH   64     // channels (K)
#define NTHR  256    // 4 waves; __launch_bounds__(256,4) -> 128 VGPR cap
#define WWC   (WW*CCH)
#define NOUT  (600*WW)

typedef __attribute__((ext_vector_type(8))) short short8;
typedef __attribute__((ext_vector_type(4))) float f32x4;

// R10 = R8/R9 design, third submission (R8/R9 were infra failures: push
// layer flaky, cf. R3->R4 clearing unchanged; kernel audited clean).
// Design: R7 skeleton (block=(bs,i-half,q-half), atomics epilogue, XCD
// swizzle; spill-free at VGPR 44 / WRITE_SIZE 8.5MB) with the memory
// dependency chain cut from 11 serial wait-rounds to 4:
//   staging: 2 rounds of 32 loads (was 8 rounds of 8)
//   A-gather: tiles {0,1} batched (32 loads) + tile 2 (was 3 rounds of 16)
// All wide arrays live inside ONE scope, never across a phase/barrier (the
// R2/R4/R5/R6 spill trigger). Target VGPR <= 84 so HW co-schedules 6
// blocks/CU (LDS 25.4KB x 6 = 152KB).
// LDS row layout: pitch 64 bf16 (128B), 16B-granule XOR swizzle (g ^ (m&7));
// bank-uniform for b128 writes and b128 fragment reads (proven R1/R2).

__device__ __forceinline__ unsigned int encf(float f) {
  unsigned int b = __float_as_uint(f);
  return (b & 0x80000000u) ? ~b : (b | 0x80000000u);  // monotone f32 -> u32
}

// Stage one Q row: 64 strided floats in 2 rounds of 32, bf16-pack, swizzled
// b128 writes; returns rsqrt(sumsq).
__device__ __forceinline__ float stage_row32(const float* __restrict__ gp,
                                             unsigned short* __restrict__ dst,
                                             int sw) {
  float ss = 0.f;
  #pragma unroll
  for (int h = 0; h < 2; ++h) {
    float v[32];
    #pragma unroll
    for (int j = 0; j < 32; ++j) v[j] = gp[(h * 32 + j) * WW];  // coalesced
    #pragma unroll
    for (int c = 0; c < 4; ++c) {
      unsigned int u[4];
      #pragma unroll
      for (int jj = 0; jj < 4; ++jj) {
        float x = v[c * 8 + 2 * jj], y = v[c * 8 + 2 * jj + 1];
        ss += x * x + y * y;
        __hip_bfloat162 b2 = __float22bfloat162_rn(make_float2(x, y));
        u[jj] = *(unsigned int*)&b2;
      }
      *(uint4*)&dst[((h * 4 + c) ^ sw) * 8] = make_uint4(u[0], u[1], u[2], u[3]);
    }
  }
  return rsqrtf(ss);
}

__device__ __forceinline__ void zero_row(unsigned short* __restrict__ dst) {
  #pragma unroll
  for (int c = 0; c < 8; ++c)
    *(uint4*)&dst[c * 8] = make_uint4(0u, 0u, 0u, 0u);
}

// convert 16 gathered floats -> one A fragment pair + row-sumsq (own lane part)
__device__ __forceinline__ void packA(const float* w, short8& af0, short8& af1,
                                      float& ssout) {
  unsigned int u[8];
  float ss = 0.f;
  #pragma unroll
  for (int jj = 0; jj < 8; ++jj) {
    float x = w[2 * jj], y = w[2 * jj + 1];
    ss += x * x + y * y;
    __hip_bfloat162 b2 = __float22bfloat162_rn(make_float2(x, y));
    u[jj] = *(unsigned int*)&b2;
  }
  uint4 t0 = make_uint4(u[0], u[1], u[2], u[3]);
  uint4 t1 = make_uint4(u[4], u[5], u[6], u[7]);
  af0 = *(short8*)&t0;
  af1 = *(short8*)&t1;
  ssout = ss;
}

__device__ __forceinline__ void epilogueAtomic(f32x4 mx, float invA, int tileBase,
                                               int quad, int l15,
                                               unsigned int* __restrict__ outb) {
  #pragma unroll
  for (int d = 1; d < 16; d <<= 1) {
    #pragma unroll
    for (int r = 0; r < 4; ++r) mx[r] = fmaxf(mx[r], __shfl_xor(mx[r], d));
  }
  const float iv0 = __shfl(invA, 4 * quad + 0);
  const float iv1 = __shfl(invA, 4 * quad + 1);
  const float iv2 = __shfl(invA, 4 * quad + 2);
  const float iv3 = __shfl(invA, 4 * quad + 3);
  if (l15 == 0) {
    const int mb = tileBase + 4 * quad;
    if (mb + 0 < WW) atomicMax(&outb[mb + 0], encf(mx[0] * iv0));
    if (mb + 1 < WW) atomicMax(&outb[mb + 1], encf(mx[1] * iv1));
    if (mb + 2 < WW) atomicMax(&outb[mb + 2], encf(mx[2] * iv2));
    if (mb + 3 < WW) atomicMax(&outb[mb + 3], encf(mx[3] * iv3));
  }
}

__global__ __launch_bounds__(NTHR, 4) void cossim_max_kernel(
    const float* __restrict__ support, const float* __restrict__ query,
    unsigned int* __restrict__ outenc)
{
  __shared__ __align__(16) unsigned short Q_sh[192 * CCH];  // 24576 B
  __shared__ float inv_q[192];                              //   768 B

  const int tid  = threadIdx.x;
  const int lane = tid & 63;
  const int wv   = tid >> 6;     // 0..3
  const int l15  = lane & 15;
  const int quad = lane >> 4;

  // XCD-chunk swizzle: 2400 = 8*300; the 4 sub-blocks of one bs run
  // adjacently on one XCD -> duplicate S/Q reads hit that XCD's L2/L3.
  const int b  = ((int)blockIdx.x & 7) * 300 + ((int)blockIdx.x >> 3);
  const int bs = b >> 2;
  const int qh = b & 1;          // q-half
  const int ih = (b >> 1) & 1;   // i-half
  const int qBase = qh * 192;
  const int mBase = ih * 192;

  const float* sg = support + (size_t)bs * WWC;
  const float* qg = query   + (size_t)bs * WWC;

  // ---- Q staging: threads 0..191, one row each, 2 wide rounds ----
  const int nreal = qh ? (WW - 192) : 192;   // 169 real rows in half 1
  if (tid < 192) {
    if (tid < nreal) {
      inv_q[tid] = stage_row32(qg + qBase + tid, &Q_sh[tid * CCH], tid & 7);
    } else if (tid < 176) {      // rows 169..175 read by tile 10 -> zero
      zero_row(&Q_sh[tid * CCH]);
      inv_q[tid] = 0.f;
    }                            // rows 176..191 never read (NTB=11)
  }

  // ---- A fragments: 3 i-tiles/wave; tiles {0,1} batched, tile 2 alone ----
  short8 af[3][2]; float invA[3];
  {
    const int iG0 = mBase + 16 * (3 * wv + 0) + l15;
    const int iG1 = mBase + 16 * (3 * wv + 1) + l15;
    const int iG2 = mBase + 16 * (3 * wv + 2) + l15;
    const bool v0 = iG0 < WW, v1 = iG1 < WW, v2 = iG2 < WW;
    float ss0, ss1, ss2;
    {
      float w[32];
      const float* s0 = sg + iG0;
      const float* s1 = sg + iG1;
      if (v0) {
        #pragma unroll
        for (int j = 0; j < 8; ++j) w[j]     = s0[(8 * quad + j) * WW];
        #pragma unroll
        for (int j = 0; j < 8; ++j) w[8 + j] = s0[(32 + 8 * quad + j) * WW];
      } else {
        #pragma unroll
        for (int j = 0; j < 16; ++j) w[j] = 0.f;
      }
      if (v1) {
        #pragma unroll
        for (int j = 0; j < 8; ++j) w[16 + j] = s1[(8 * quad + j) * WW];
        #pragma unroll
        for (int j = 0; j < 8; ++j) w[24 + j] = s1[(32 + 8 * quad + j) * WW];
      } else {
        #pragma unroll
        for (int j = 0; j < 16; ++j) w[16 + j] = 0.f;
      }
      packA(&w[0],  af[0][0], af[0][1], ss0);
      packA(&w[16], af[1][0], af[1][1], ss1);
    }
    {
      float w[16];
      const float* s2 = sg + iG2;
      if (v2) {
        #pragma unroll
        for (int j = 0; j < 8; ++j) w[j]     = s2[(8 * quad + j) * WW];
        #pragma unroll
        for (int j = 0; j < 8; ++j) w[8 + j] = s2[(32 + 8 * quad + j) * WW];
      } else {
        #pragma unroll
        for (int j = 0; j < 16; ++j) w[j] = 0.f;
      }
      packA(&w[0], af[2][0], af[2][1], ss2);
    }
    ss0 += __shfl_xor(ss0, 16); ss0 += __shfl_xor(ss0, 32);
    ss1 += __shfl_xor(ss1, 16); ss1 += __shfl_xor(ss1, 32);
    ss2 += __shfl_xor(ss2, 16); ss2 += __shfl_xor(ss2, 32);
    invA[0] = v0 ? rsqrtf(ss0) : 0.f;
    invA[1] = v1 ? rsqrtf(ss1) : 0.f;
    invA[2] = v2 ? rsqrtf(ss2) : 0.f;
  }

  __syncthreads();

  // ---- compute: NTB q-tiles from swizzled LDS; 3 MFMA pairs per B-frag ----
  const int boff0 = l15 * CCH + ((quad       ^ (l15 & 7)) * 8);
  const int boff1 = l15 * CCH + (((4 + quad) ^ (l15 & 7)) * 8);
  const int NTB = qh ? 11 : 12;
  // half1 tile 10 covers global q-rows 352+l15 -> pad for l15 >= 9
  const float lastbias = (qh && l15 >= 9) ? -1e30f : 0.f;

  f32x4 mx0 = {-3e38f, -3e38f, -3e38f, -3e38f};
  f32x4 mx1 = mx0, mx2 = mx0;

  for (int t = 0; t < NTB; ++t) {
    const int nb = t * 16 * CCH;
    short8 b0 = *(const short8*)&Q_sh[nb + boff0];
    short8 b1 = *(const short8*)&Q_sh[nb + boff1];
    const float qs = inv_q[t * 16 + l15];
    const float bb = (t == NTB - 1) ? lastbias : 0.f;
    f32x4 a0 = {0.f, 0.f, 0.f, 0.f}, a1 = a0, a2 = a0;
    __builtin_amdgcn_s_setprio(1);
    a0 = __builtin_amdgcn_mfma_f32_16x16x32_bf16(af[0][0], b0, a0, 0, 0, 0);
    a0 = __builtin_amdgcn_mfma_f32_16x16x32_bf16(af[0][1], b1, a0, 0, 0, 0);
    a1 = __builtin_amdgcn_mfma_f32_16x16x32_bf16(af[1][0], b0, a1, 0, 0, 0);
    a1 = __builtin_amdgcn_mfma_f32_16x16x32_bf16(af[1][1], b1, a1, 0, 0, 0);
    a2 = __builtin_amdgcn_mfma_f32_16x16x32_bf16(af[2][0], b0, a2, 0, 0, 0);
    a2 = __builtin_amdgcn_mfma_f32_16x16x32_bf16(af[2][1], b1, a2, 0, 0, 0);
    __builtin_amdgcn_s_setprio(0);
    #pragma unroll
    for (int r = 0; r < 4; ++r) {
      mx0[r] = fmaxf(mx0[r], a0[r] * qs + bb);
      mx1[r] = fmaxf(mx1[r], a1[r] * qs + bb);
      mx2[r] = fmaxf(mx2[r], a2[r] * qs + bb);
    }
  }

  unsigned int* outb = outenc + (size_t)bs * WW;
  epilogueAtomic(mx0, invA[0], mBase + 16 * (3 * wv + 0), quad, l15, outb);
  epilogueAtomic(mx1, invA[1], mBase + 16 * (3 * wv + 1), quad, l15, outb);
  epilogueAtomic(mx2, invA[2], mBase + 16 * (3 * wv + 2), quad, l15, outb);
}

__global__ void cossim_decode(unsigned int* __restrict__ p) {
  const int i = blockIdx.x * blockDim.x + threadIdx.x;
  if (i < NOUT) {
    const unsigned int u = p[i];
    p[i] = (u & 0x80000000u) ? (u & 0x7fffffffu) : ~u;  // inverse of encf
  }
}

extern "C" void kernel_launch(void* const* d_in, const int* in_sizes, int n_in,
                              void* d_out, int out_size, void* d_ws, size_t ws_size,
                              hipStream_t stream) {
  const float* support = (const float*)d_in[0];
  const float* query   = (const float*)d_in[1];
  unsigned int* outenc = (unsigned int*)d_out;
  hipMemsetAsync(d_out, 0, (size_t)out_size, stream);  // encf identity (all encf>0)
  dim3 grid(2400), block(NTHR);
  hipLaunchKernelGGL(cossim_max_kernel, grid, block, 0, stream,
                     support, query, outenc);
  dim3 dgrid((NOUT + 255) / 256), dblock(256);
  hipLaunchKernelGGL(cossim_decode, dgrid, dblock, 0, stream, outenc);
}